// Round 2
// baseline (665.067 us; speedup 1.0000x reference)
//
#include <hip/hip_runtime.h>

#define BB 256
#define SS 1024
#define TT 128
#define ST 126          // START state
#define IMIN -10000.0f
#define L2E 1.4426950408889634f
#define LN2f 0.6931471805599453f

// One block per batch. tid = 2*i + h : i = state row (0..127), h = j-half (0/1).
// alpha kept in base-2 units A = alpha * log2(e).
// P[i][j] = 2^(T2[i][j] - rowmax_i) precomputed in registers (64 per thread).
// Per step: tot_i = sum_j P[i][j] * v[j],  v[j] = 2^(A[j] - vsh)  (vsh lagged max)
//           A_i <- log2e*feat + rowmax_i + vsh + log2(tot_i)
__global__ __launch_bounds__(256) void crf_fwd(const float* __restrict__ feats,
                                               const int* __restrict__ blen,
                                               const float* __restrict__ trans,
                                               float* __restrict__ out)
{
    const int tid = threadIdx.x;
    const int i   = tid >> 1;
    const int h   = tid & 1;
    const int b   = blockIdx.x;

    __shared__ __align__(16) float vbuf[2][TT];
    __shared__ __align__(16) float wmax[2][4];
    __shared__ __align__(16) float featbuf[2][8 * TT];
    __shared__ __align__(16) float wout[TT];

    const float* fb = feats + (size_t)b * (SS * TT);
    const int L = blen[b];

    // stage feature chunk 0 (steps 0..7): 256 threads x float4 = 1024 floats
    {
        float4 f0 = *(const float4*)(fb + tid * 4);
        *(float4*)(&featbuf[0][tid * 4]) = f0;
    }

    // Load transitions half-row into registers, convert to base-2 (T2 = trans*log2e)
    float P[64];
    {
        const float* trow = trans + i * TT + h * 64;
        #pragma unroll
        for (int k = 0; k < 64; k += 4) {
            float4 tv = *(const float4*)(trow + k);
            P[k+0] = tv.x * L2E; P[k+1] = tv.y * L2E;
            P[k+2] = tv.z * L2E; P[k+3] = tv.w * L2E;
        }
    }

    // rowmax (for P normalization) and EXACT step-0 row max m0 (alpha0 is a
    // -10000-gapped delta on START; the rowmax+maxA bound underflows here).
    float rmaxh = -3.4e38f, m0h = -3.4e38f;
    #pragma unroll
    for (int k = 0; k < 64; ++k) {
        rmaxh = fmaxf(rmaxh, P[k]);
        float a0 = ((h * 64 + k) == ST) ? 0.f : IMIN * L2E;
        m0h = fmaxf(m0h, P[k] + a0);
    }
    float rowmax = fmaxf(rmaxh, __shfl_xor(rmaxh, 1));
    float m0     = fmaxf(m0h,  __shfl_xor(m0h, 1));

    float s0h = 0.f;
    #pragma unroll
    for (int k = 0; k < 64; ++k) {
        float a0 = ((h * 64 + k) == ST) ? 0.f : IMIN * L2E;
        s0h += exp2f(P[k] + a0 - m0);
    }
    float tot0 = s0h + __shfl_xor(s0h, 1);

    #pragma unroll
    for (int k = 0; k < 64; ++k) P[k] = exp2f(P[k] - rowmax);

    __syncthreads();  // featbuf[0] visible

    // A after step 0 (exact)
    float A = fmaf(featbuf[0][i], L2E, m0 + log2f(tot0));

    // block-wide max(A) -> initial shift
    float m = A;
    #pragma unroll
    for (int off = 2; off < 64; off <<= 1) m = fmaxf(m, __shfl_xor(m, off));
    if ((tid & 63) == 0) wmax[0][tid >> 6] = m;
    __syncthreads();
    float4 wm4 = *(const float4*)(&wmax[0][0]);
    float lagm = fmaxf(fmaxf(wm4.x, wm4.y), fmaxf(wm4.z, wm4.w));
    float vsh  = lagm;
    if (h == 0) vbuf[0][i] = exp2f(A - lagm);
    __syncthreads();

    int cur = 0;
    float4 fnx = *(const float4*)(fb + 8 * TT + tid * 4);  // prefetch chunk 1

    for (int c = 0; ; ++c) {
        const int sLo = (c == 0) ? 1 : 8 * c;
        const int sHi = min(8 * c + 8, L);
        for (int s = sLo; s < sHi; ++s) {
            // matvec: tot_i = sum_j P[i][j] * v[j]
            float a0 = 0.f, a1 = 0.f, a2 = 0.f, a3 = 0.f;
            const float* vb = &vbuf[cur][h * 64];
            #pragma unroll
            for (int k = 0; k < 64; k += 4) {
                float4 vv = *(const float4*)(vb + k);
                a0 = fmaf(P[k+0], vv.x, a0);
                a1 = fmaf(P[k+1], vv.y, a1);
                a2 = fmaf(P[k+2], vv.z, a2);
                a3 = fmaf(P[k+3], vv.w, a3);
            }
            float part = (a0 + a1) + (a2 + a3);
            float tot  = part + __shfl_xor(part, 1);   // combine j-halves (lane pair)

            float fv   = featbuf[c & 1][((s & 7) << 7) + i];
            float Anew = fmaf(fv, L2E, (rowmax + vsh) + log2f(tot));

            // write next v with lagged shift (bound, not exact max)
            if (h == 0) vbuf[cur ^ 1][i] = exp2f(Anew - lagm);

            // block max of Anew -> shift for the step after next
            float mm = Anew;
            #pragma unroll
            for (int off = 2; off < 64; off <<= 1) mm = fmaxf(mm, __shfl_xor(mm, off));
            if ((tid & 63) == 0) wmax[cur ^ 1][tid >> 6] = mm;
            __syncthreads();   // single barrier: covers vbuf[nxt] + wmax[nxt]
            float4 w4 = *(const float4*)(&wmax[cur ^ 1][0]);
            vsh  = lagm;
            lagm = fmaxf(fmaxf(w4.x, w4.y), fmaxf(w4.z, w4.w));
            A = Anew;
            cur ^= 1;
        }
        if (8 * c + 8 >= L) break;
        // stage next chunk, prefetch the one after
        *(float4*)(&featbuf[(c + 1) & 1][tid * 4]) = fnx;
        int cn = min(c + 2, (SS / 8) - 1);
        fnx = *(const float4*)(fb + cn * 8 * TT + tid * 4);
        __syncthreads();
    }

    // epilogue: out = ln2 * log2 sum_j 2^(A[j] + log2e*trans[END][j])
    float w = fmaf(trans[(TT - 1) * TT + i], L2E, A);
    if (h == 0) wout[i] = w;
    __syncthreads();
    if (tid < 64) {
        float w0 = wout[tid], w1 = wout[tid + 64];
        float mm = fmaxf(w0, w1);
        #pragma unroll
        for (int off = 1; off < 64; off <<= 1) mm = fmaxf(mm, __shfl_xor(mm, off));
        float ss = exp2f(w0 - mm) + exp2f(w1 - mm);
        #pragma unroll
        for (int off = 1; off < 64; off <<= 1) ss += __shfl_xor(ss, off);
        if (tid == 0) out[b] = (mm + log2f(ss)) * LN2f;
    }
}

extern "C" void kernel_launch(void* const* d_in, const int* in_sizes, int n_in,
                              void* d_out, int out_size, void* d_ws, size_t ws_size,
                              hipStream_t stream) {
    const float* feats = (const float*)d_in[0];
    const int*   blen  = (const int*)d_in[1];
    const float* trans = (const float*)d_in[2];
    float*       o     = (float*)d_out;
    crf_fwd<<<dim3(BB), dim3(256), 0, stream>>>(feats, blen, trans, o);
}

// Round 3
// 557.220 us; speedup vs baseline: 1.1935x; 1.1935x over previous
//
#include <hip/hip_runtime.h>

#define BB 256
#define SS 1024
#define TT 128
#define ST 126          // START state
#define IMIN -10000.0f
#define L2E 1.4426950408889634f
#define LN2f 0.6931471805599453f
#define QS 40           // padded quarter stride (floats): 32 data + 8 pad
                        // 160B: 16B-aligned, quarter bases hit disjoint banks

// One block per batch, 512 threads. tid = 4*i + q : i = state row (0..127),
// q = j-quarter (0..3). alpha kept implicitly: v[j] = 2^(A[j] - sh), sh uniform.
// P[i][j] = 2^(trans*log2e - rowmax_i) in registers (32 per thread).
// Step:  tot_i = sum_j P[i][j] v[j]   (8x float4 FMA + 2 quad shuffles)
//        v'[i] = tot_i * 2^(feat*L2E + rowmax_i + sh - sh')   (1 mul on chain)
//        sh'   = sh + log2(block max v)   (1-step-lagged, off critical path)
__global__ __launch_bounds__(512) void crf_fwd(const float* __restrict__ feats,
                                               const int* __restrict__ blen,
                                               const float* __restrict__ trans,
                                               float* __restrict__ out)
{
    const int tid = threadIdx.x;
    const int i   = tid >> 2;
    const int q   = tid & 3;
    const int b   = blockIdx.x;

    __shared__ __align__(16) float vbuf[2][4 * QS];
    __shared__ __align__(16) float wmax[2][8];
    __shared__ __align__(16) float featbuf[2][8 * TT];
    __shared__ __align__(16) float wout[TT];

    const float* fb = feats + (size_t)b * (SS * TT);
    const int L = blen[b];

    // stage feature chunk 0 (steps 0..7): 512 threads x float2 = 1024 floats
    *(float2*)(&featbuf[0][tid * 2]) = *(const float2*)(fb + tid * 2);

    // transitions quarter-row -> registers, base-2 units
    float P[32];
    {
        const float* trow = trans + i * TT + q * 32;
        #pragma unroll
        for (int k = 0; k < 32; k += 4) {
            float4 tv = *(const float4*)(trow + k);
            P[k+0] = tv.x * L2E; P[k+1] = tv.y * L2E;
            P[k+2] = tv.z * L2E; P[k+3] = tv.w * L2E;
        }
    }

    // per-row max (P normalization) and EXACT step-0 row max (alpha0 is a
    // -10000-gapped delta on START; a bound-based shift underflows here)
    float rmaxh = -3.4e38f, m0h = -3.4e38f;
    #pragma unroll
    for (int k = 0; k < 32; ++k) {
        rmaxh = fmaxf(rmaxh, P[k]);
        float a0 = ((q * 32 + k) == ST) ? 0.f : IMIN * L2E;
        m0h = fmaxf(m0h, P[k] + a0);
    }
    rmaxh = fmaxf(rmaxh, __shfl_xor(rmaxh, 1));
    rmaxh = fmaxf(rmaxh, __shfl_xor(rmaxh, 2));
    const float rowmax = rmaxh;
    m0h = fmaxf(m0h, __shfl_xor(m0h, 1));
    m0h = fmaxf(m0h, __shfl_xor(m0h, 2));
    const float m0 = m0h;

    float s0h = 0.f;
    #pragma unroll
    for (int k = 0; k < 32; ++k) {
        float a0 = ((q * 32 + k) == ST) ? 0.f : IMIN * L2E;
        s0h += exp2f(P[k] + a0 - m0);
    }
    s0h += __shfl_xor(s0h, 1);
    s0h += __shfl_xor(s0h, 2);
    const float tot0 = s0h;

    #pragma unroll
    for (int k = 0; k < 32; ++k) P[k] = exp2f(P[k] - rowmax);

    __syncthreads();  // featbuf[0] visible

    // A after step 0 (exact)
    float A1 = fmaf(featbuf[0][i], L2E, m0 + log2f(tot0));

    // exact block max(A1) -> initial shift
    float m = A1;
    #pragma unroll
    for (int off = 4; off < 64; off <<= 1) m = fmaxf(m, __shfl_xor(m, off));
    if ((tid & 63) == 0) wmax[1][tid >> 6] = m;
    __syncthreads();
    float sh;
    {
        float4 wa = *(const float4*)(&wmax[1][0]);
        float4 wb = *(const float4*)(&wmax[1][4]);
        sh = fmaxf(fmaxf(fmaxf(wa.x, wa.y), fmaxf(wa.z, wa.w)),
                   fmaxf(fmaxf(wb.x, wb.y), fmaxf(wb.z, wb.w)));
    }
    float v1 = exp2f(A1 - sh);
    if (q == 0) vbuf[0][((i >> 5) * QS) + (i & 31)] = v1;
    float wv = v1;
    #pragma unroll
    for (int off = 4; off < 64; off <<= 1) wv = fmaxf(wv, __shfl_xor(wv, off));
    if ((tid & 63) == 0) wmax[0][tid >> 6] = wv;
    __syncthreads();

    int cur = 0;
    float2 fnx = *(const float2*)(fb + 8 * TT + tid * 2);  // prefetch chunk 1

    for (int ch = 0; ; ++ch) {
        const int sLo = (ch == 0) ? 1 : 8 * ch;
        const int sHi = min(8 * ch + 8, L);
        for (int s = sLo; s < sHi; ++s) {
            // matvec over this thread's quarter: tot_i = sum_j P[i][j] * v[j]
            const float* vb = &vbuf[cur][q * QS];
            float a0 = 0.f, a1 = 0.f, a2 = 0.f, a3 = 0.f;
            #pragma unroll
            for (int k = 0; k < 32; k += 4) {
                float4 vv = *(const float4*)(vb + k);
                a0 = fmaf(P[k+0], vv.x, a0);
                a1 = fmaf(P[k+1], vv.y, a1);
                a2 = fmaf(P[k+2], vv.z, a2);
                a3 = fmaf(P[k+3], vv.w, a3);
            }

            // shift update from previous step's block max of v (off chain)
            float4 wa = *(const float4*)(&wmax[cur][0]);
            float4 wb = *(const float4*)(&wmax[cur][4]);
            float maxv = fmaxf(fmaxf(fmaxf(wa.x, wa.y), fmaxf(wa.z, wa.w)),
                               fmaxf(fmaxf(wb.x, wb.y), fmaxf(wb.z, wb.w)));
            float shn = sh + log2f(maxv);
            float fv  = featbuf[ch & 1][((s & 7) << 7) + i];
            float cf  = exp2f(fmaf(fv, L2E, rowmax + sh - shn));  // off chain

            float part = (a0 + a1) + (a2 + a3);
            part += __shfl_xor(part, 1);
            part += __shfl_xor(part, 2);      // tot in all 4 quad lanes

            float vn = cf * part;             // the only chain op after matvec
            if (q == 0) vbuf[cur ^ 1][((i >> 5) * QS) + (i & 31)] = vn;

            float wm = vn;
            #pragma unroll
            for (int off = 4; off < 64; off <<= 1) wm = fmaxf(wm, __shfl_xor(wm, off));
            if ((tid & 63) == 0) wmax[cur ^ 1][tid >> 6] = wm;

            __syncthreads();   // single barrier: vbuf[nxt] + wmax[nxt] visible
            sh = shn;
            cur ^= 1;
        }
        if (8 * ch + 8 >= L) break;
        // stage next chunk, prefetch the one after
        *(float2*)(&featbuf[(ch + 1) & 1][tid * 2]) = fnx;
        int cn = min(ch + 2, (SS / 8) - 1);
        fnx = *(const float2*)(fb + cn * 8 * TT + tid * 2);
        __syncthreads();
    }

    // epilogue: out = ln2 * log2 sum_j 2^(A[j] + log2e*trans[END][j]),
    // A[j] = sh + log2(v[j])  (v==0 -> -inf -> contributes 0, benign)
    float vfin = vbuf[cur][((i >> 5) * QS) + (i & 31)];
    float w = fmaf(trans[(TT - 1) * TT + i], L2E, sh + log2f(vfin));
    if (q == 0) wout[i] = w;
    __syncthreads();
    if (tid < 64) {
        float w0 = wout[tid], w1 = wout[tid + 64];
        float mm = fmaxf(w0, w1);
        #pragma unroll
        for (int off = 1; off < 64; off <<= 1) mm = fmaxf(mm, __shfl_xor(mm, off));
        float ss = exp2f(w0 - mm) + exp2f(w1 - mm);
        #pragma unroll
        for (int off = 1; off < 64; off <<= 1) ss += __shfl_xor(ss, off);
        if (tid == 0) out[b] = (mm + log2f(ss)) * LN2f;
    }
}

extern "C" void kernel_launch(void* const* d_in, const int* in_sizes, int n_in,
                              void* d_out, int out_size, void* d_ws, size_t ws_size,
                              hipStream_t stream) {
    const float* feats = (const float*)d_in[0];
    const int*   blen  = (const int*)d_in[1];
    const float* trans = (const float*)d_in[2];
    float*       o     = (float*)d_out;
    crf_fwd<<<dim3(BB), dim3(512), 0, stream>>>(feats, blen, trans, o);
}